// Round 1
// baseline (581.128 us; speedup 1.0000x reference)
//
#include <hip/hip_runtime.h>
#include <math.h>

#define HIDDEN 64
#define TARGET 10

// ---------------------------------------------------------------------------
// K1: precompute small tables.
//  tbl[0..63]   = hw_src[k] = W_gat[k,:] . att_src   (a_src = x . hw_src)
//  tbl[64..127] = hw_dst[k] = W_gat[k,:] . att_dst
//  tbl[128..135]= tbl_travel[t] = emb_travel[t,:] . w_e[0:64]
//  tbl[136..138]= c0,c1,c2 = w_e[64..66]  (duration, tst, tet coefficients)
// where w_e[k] = W_edge[k,:] . att_edge
// ---------------------------------------------------------------------------
__global__ void k_tables(const float* __restrict__ W_gat,
                         const float* __restrict__ att_src,
                         const float* __restrict__ att_dst,
                         const float* __restrict__ W_edge,
                         const float* __restrict__ att_edge,
                         const float* __restrict__ emb_travel,
                         float* __restrict__ tbl) {
    __shared__ float we_s[67];
    int t = threadIdx.x;
    if (t < 64) {
        float s1 = 0.f, s2 = 0.f;
        for (int j = 0; j < 64; j++) {
            float w = W_gat[t * 64 + j];
            s1 += w * att_src[j];
            s2 += w * att_dst[j];
        }
        tbl[t] = s1;
        tbl[64 + t] = s2;
    }
    if (t < 67) {
        float s = 0.f;
        for (int j = 0; j < 64; j++) s += W_edge[t * 64 + j] * att_edge[j];
        we_s[t] = s;
    }
    __syncthreads();
    if (t < 8) {
        float s = 0.f;
        for (int k = 0; k < 64; k++) s += emb_travel[t * 64 + k] * we_s[k];
        tbl[128 + t] = s;
    }
    if (t == 0) {
        tbl[136] = we_s[64];
        tbl[137] = we_s[65];
        tbl[138] = we_s[66];
    }
}

// ---------------------------------------------------------------------------
// K2: per-node. One wave per node.
//  x = relu(emb_act[act] + emb_loc[loc]);  h = x @ W_gat (W_gat staged in LDS)
//  a_src = x . hw_src ; a_dst = x . hw_dst  (shuffle butterfly reduce)
// ---------------------------------------------------------------------------
__global__ void k_nodes(const int* __restrict__ act, const int* __restrict__ loc,
                        const float* __restrict__ emb_act,
                        const float* __restrict__ emb_loc,
                        const float* __restrict__ W_gat,
                        const float* __restrict__ tbl,
                        float* __restrict__ h,
                        float* __restrict__ a_src, float* __restrict__ a_dst,
                        int N) {
    __shared__ float Wl[64 * 64];
    for (int i = threadIdx.x; i < 64 * 64; i += blockDim.x) Wl[i] = W_gat[i];
    __syncthreads();
    int lane = threadIdx.x & 63;
    int wid = (blockIdx.x * blockDim.x + threadIdx.x) >> 6;
    int nw = (gridDim.x * blockDim.x) >> 6;
    float hs = tbl[lane], hd = tbl[64 + lane];
    for (int n = wid; n < N; n += nw) {
        int a = act[n], l = loc[n];
        float x = emb_act[a * 64 + lane] + emb_loc[l * 64 + lane];
        x = x > 0.f ? x : 0.f;
        float acc = 0.f;
#pragma unroll
        for (int k = 0; k < 64; k++) acc += __shfl(x, k, 64) * Wl[k * 64 + lane];
        h[(size_t)n * 64 + lane] = acc;
        float ps = x * hs, pd = x * hd;
#pragma unroll
        for (int o = 32; o > 0; o >>= 1) {
            ps += __shfl_xor(ps, o, 64);
            pd += __shfl_xor(pd, o, 64);
        }
        if (lane == 0) { a_src[n] = ps; a_dst[n] = pd; }
    }
}

// ---------------------------------------------------------------------------
// K3: per-edge, one wave per edge. alpha computed inline (no max pass:
// softmax is shift-invariant and |alpha| << 1 for these scales).
//  ev = exp(leaky_relu(a_src[s] + a_dst[d] + a_edge, 0.2))
//  outacc[d,:] += ev * h[s,:]   (native f32 atomics)
//  denom[d]    += ev
// ---------------------------------------------------------------------------
__global__ void k_edges(const int* __restrict__ src, const int* __restrict__ dst,
                        const int* __restrict__ travel,
                        const float* __restrict__ dur,
                        const float* __restrict__ tst,
                        const float* __restrict__ tet,
                        const float* __restrict__ a_src,
                        const float* __restrict__ a_dst,
                        const float* __restrict__ tbl,
                        const float* __restrict__ h,
                        float* __restrict__ outacc, float* __restrict__ denom,
                        int E) {
    int lane = threadIdx.x & 63;
    int wid = (blockIdx.x * blockDim.x + threadIdx.x) >> 6;
    int nw = (gridDim.x * blockDim.x) >> 6;
    float c0 = tbl[136], c1 = tbl[137], c2 = tbl[138];
    for (int e = wid; e < E; e += nw) {
        int s = src[e], d = dst[e];
        float al = a_src[s] + a_dst[d] + tbl[128 + travel[e]]
                 + c0 * dur[e] + c1 * tst[e] + c2 * tet[e];
        al = al > 0.f ? al : 0.2f * al;
        float ev = __expf(al);
        unsafeAtomicAdd(&outacc[(size_t)d * 64 + lane], ev * h[(size_t)s * 64 + lane]);
        if (lane == 0) unsafeAtomicAdd(&denom[d], ev);
    }
}

// ---------------------------------------------------------------------------
// K4: per-graph mean pool. batch is sorted -> binary search range.
//  x2[n] = relu(outacc[n]/max(denom[n],1e-16) + b_gat); pooled = mean(x2)
// ---------------------------------------------------------------------------
__global__ void k_pool(const float* __restrict__ outacc,
                       const float* __restrict__ denom,
                       const float* __restrict__ b_gat,
                       const int* __restrict__ batch, int N,
                       float* __restrict__ pooled) {
    int g = blockIdx.x;
    int lane = threadIdx.x;
    int lo = 0, hi = N;
    while (lo < hi) { int mid = (lo + hi) >> 1; if (batch[mid] < g) lo = mid + 1; else hi = mid; }
    int start = lo;
    hi = N;
    while (lo < hi) { int mid = (lo + hi) >> 1; if (batch[mid] < g + 1) lo = mid + 1; else hi = mid; }
    int end = lo;
    float b = b_gat[lane];
    float sum = 0.f;
    for (int n = start; n < end; n++) {
        float dn = denom[n];
        dn = dn > 1e-16f ? dn : 1e-16f;
        float v = outacc[(size_t)n * 64 + lane] / dn + b;
        sum += v > 0.f ? v : 0.f;
    }
    float cnt = (float)(end - start);
    pooled[g * 64 + lane] = sum / (cnt > 1.f ? cnt : 1.f);
}

// ---------------------------------------------------------------------------
// K5: logits = pooled @ W_fc + b_fc ; out = log_softmax(logits)
// One wave per graph; butterfly reductions give every lane all 10 logits.
// ---------------------------------------------------------------------------
__global__ void k_fc(const float* __restrict__ pooled,
                     const float* __restrict__ W_fc,
                     const float* __restrict__ b_fc,
                     float* __restrict__ out, int G) {
    int lane = threadIdx.x & 63;
    int wid = (blockIdx.x * blockDim.x + threadIdx.x) >> 6;
    int nw = (gridDim.x * blockDim.x) >> 6;
    for (int g = wid; g < G; g += nw) {
        float p = pooled[g * 64 + lane];
        float logit[TARGET];
#pragma unroll
        for (int t = 0; t < TARGET; t++) {
            float v = p * W_fc[lane * TARGET + t];
#pragma unroll
            for (int o = 32; o > 0; o >>= 1) v += __shfl_xor(v, o, 64);
            logit[t] = v + b_fc[t];
        }
        float m = logit[0];
#pragma unroll
        for (int t = 1; t < TARGET; t++) m = fmaxf(m, logit[t]);
        float se = 0.f;
#pragma unroll
        for (int t = 0; t < TARGET; t++) se += expf(logit[t] - m);
        float lse = m + logf(se);
#pragma unroll
        for (int t = 0; t < TARGET; t++)
            if (lane == t) out[g * TARGET + t] = logit[t] - lse;
    }
}

extern "C" void kernel_launch(void* const* d_in, const int* in_sizes, int n_in,
                              void* d_out, int out_size, void* d_ws, size_t ws_size,
                              hipStream_t stream) {
    const int*   act        = (const int*)d_in[0];
    const int*   loc        = (const int*)d_in[1];
    const int*   travel     = (const int*)d_in[2];
    const float* dur        = (const float*)d_in[3];
    const float* tst        = (const float*)d_in[4];
    const float* tet        = (const float*)d_in[5];
    const int*   ei         = (const int*)d_in[6];
    const int*   batch      = (const int*)d_in[7];
    const float* emb_act    = (const float*)d_in[8];
    const float* emb_loc    = (const float*)d_in[9];
    const float* emb_travel = (const float*)d_in[10];
    const float* W_gat      = (const float*)d_in[11];
    const float* att_src    = (const float*)d_in[12];
    const float* att_dst    = (const float*)d_in[13];
    const float* W_edge     = (const float*)d_in[14];
    const float* att_edge   = (const float*)d_in[15];
    const float* b_gat      = (const float*)d_in[16];
    const float* W_fc       = (const float*)d_in[17];
    const float* b_fc       = (const float*)d_in[18];
    float* out = (float*)d_out;

    int N = in_sizes[0];
    int E = in_sizes[2];
    int G = out_size / TARGET;
    int Npad = (N + 63) & ~63;

    float* ws = (float*)d_ws;
    size_t off = 0;
    float* tbl    = ws + off; off += 256;
    float* h      = ws + off; off += (size_t)N * 64;
    float* a_src  = ws + off; off += Npad;
    float* a_dst  = ws + off; off += Npad;
    float* denom  = ws + off; off += Npad;
    float* outacc = ws + off; off += (size_t)N * 64;
    float* pooled = ws + off; off += (size_t)G * 64;

    hipMemsetAsync(denom, 0, (size_t)Npad * sizeof(float), stream);
    hipMemsetAsync(outacc, 0, (size_t)N * 64 * sizeof(float), stream);

    k_tables<<<1, 128, 0, stream>>>(W_gat, att_src, att_dst, W_edge, att_edge,
                                    emb_travel, tbl);
    k_nodes<<<1024, 256, 0, stream>>>(act, loc, emb_act, emb_loc, W_gat, tbl,
                                      h, a_src, a_dst, N);
    k_edges<<<4096, 256, 0, stream>>>(ei, ei + E, travel, dur, tst, tet,
                                      a_src, a_dst, tbl, h, outacc, denom, E);
    k_pool<<<G, 64, 0, stream>>>(outacc, denom, b_gat, batch, N, pooled);
    k_fc<<<256, 256, 0, stream>>>(pooled, W_fc, b_fc, out, G);
}

// Round 2
// 369.337 us; speedup vs baseline: 1.5734x; 1.5734x over previous
//
#include <hip/hip_runtime.h>
#include <math.h>

#define HIDDEN 64
#define TARGET 10

// ---------------------------------------------------------------------------
// K1: precompute small tables.
//  tbl[0..63]   = hw_src[k] = W_gat[k,:] . att_src   (a_src = x . hw_src)
//  tbl[64..127] = hw_dst[k] = W_gat[k,:] . att_dst
//  tbl[128..135]= tbl_travel[t] = emb_travel[t,:] . w_e[0:64]
//  tbl[136..138]= c0,c1,c2 = w_e[64..66]  (duration, tst, tet coefficients)
// where w_e[k] = W_edge[k,:] . att_edge
// ---------------------------------------------------------------------------
__global__ void k_tables(const float* __restrict__ W_gat,
                         const float* __restrict__ att_src,
                         const float* __restrict__ att_dst,
                         const float* __restrict__ W_edge,
                         const float* __restrict__ att_edge,
                         const float* __restrict__ emb_travel,
                         float* __restrict__ tbl) {
    __shared__ float we_s[67];
    int t = threadIdx.x;
    if (t < 64) {
        float s1 = 0.f, s2 = 0.f;
        for (int j = 0; j < 64; j++) {
            float w = W_gat[t * 64 + j];
            s1 += w * att_src[j];
            s2 += w * att_dst[j];
        }
        tbl[t] = s1;
        tbl[64 + t] = s2;
    }
    if (t < 67) {
        float s = 0.f;
        for (int j = 0; j < 64; j++) s += W_edge[t * 64 + j] * att_edge[j];
        we_s[t] = s;
    }
    __syncthreads();
    if (t < 8) {
        float s = 0.f;
        for (int k = 0; k < 64; k++) s += emb_travel[t * 64 + k] * we_s[k];
        tbl[128 + t] = s;
    }
    if (t == 0) {
        tbl[136] = we_s[64];
        tbl[137] = we_s[65];
        tbl[138] = we_s[66];
    }
}

// ---------------------------------------------------------------------------
// K2: per-node. One wave per node.
//  x = relu(emb_act[act] + emb_loc[loc]);  h = x @ W_gat (W_gat staged in LDS)
//  a_src = x . hw_src ; a_dst = x . hw_dst  (shuffle butterfly reduce)
// ---------------------------------------------------------------------------
__global__ void k_nodes(const int* __restrict__ act, const int* __restrict__ loc,
                        const float* __restrict__ emb_act,
                        const float* __restrict__ emb_loc,
                        const float* __restrict__ W_gat,
                        const float* __restrict__ tbl,
                        float* __restrict__ h,
                        float* __restrict__ a_src, float* __restrict__ a_dst,
                        int N) {
    __shared__ float Wl[64 * 64];
    for (int i = threadIdx.x; i < 64 * 64; i += blockDim.x) Wl[i] = W_gat[i];
    __syncthreads();
    int lane = threadIdx.x & 63;
    int wid = (blockIdx.x * blockDim.x + threadIdx.x) >> 6;
    int nw = (gridDim.x * blockDim.x) >> 6;
    float hs = tbl[lane], hd = tbl[64 + lane];
    for (int n = wid; n < N; n += nw) {
        int a = act[n], l = loc[n];
        float x = emb_act[a * 64 + lane] + emb_loc[l * 64 + lane];
        x = x > 0.f ? x : 0.f;
        float acc = 0.f;
#pragma unroll
        for (int k = 0; k < 64; k++) acc += __shfl(x, k, 64) * Wl[k * 64 + lane];
        h[(size_t)n * 64 + lane] = acc;
        float ps = x * hs, pd = x * hd;
#pragma unroll
        for (int o = 32; o > 0; o >>= 1) {
            ps += __shfl_xor(ps, o, 64);
            pd += __shfl_xor(pd, o, 64);
        }
        if (lane == 0) { a_src[n] = ps; a_dst[n] = pd; }
    }
}

// ---------------------------------------------------------------------------
// K3a: histogram of dst -> counts[N]
// ---------------------------------------------------------------------------
__global__ void k_hist(const int* __restrict__ dst, int E,
                       int* __restrict__ counts) {
    int i = blockIdx.x * blockDim.x + threadIdx.x;
    int stride = gridDim.x * blockDim.x;
    for (int e = i; e < E; e += stride) atomicAdd(&counts[dst[e]], 1);
}

// ---------------------------------------------------------------------------
// K3b/c/d: two-level exclusive scan of counts -> rowstart[N+1], cursor[N]
// ---------------------------------------------------------------------------
__global__ void k_scanA(const int* __restrict__ counts, int N,
                        int* __restrict__ rowstart, int* __restrict__ blocksum) {
    __shared__ int s[256];
    int tid = threadIdx.x;
    int i = blockIdx.x * 256 + tid;
    int c = (i < N) ? counts[i] : 0;
    s[tid] = c;
    __syncthreads();
    for (int off = 1; off < 256; off <<= 1) {
        int v = 0;
        if (tid >= off) v = s[tid - off];
        __syncthreads();
        if (tid >= off) s[tid] += v;
        __syncthreads();
    }
    if (i < N) rowstart[i] = s[tid] - c;  // block-local exclusive
    if (tid == 255) blocksum[blockIdx.x] = s[255];
}

__global__ void k_scanB(int* __restrict__ blocksum, int NB) {
    __shared__ int s[1024];
    int tid = threadIdx.x;
    int c = (tid < NB) ? blocksum[tid] : 0;
    s[tid] = c;
    __syncthreads();
    for (int off = 1; off < 1024; off <<= 1) {
        int v = 0;
        if (tid >= off) v = s[tid - off];
        __syncthreads();
        if (tid >= off) s[tid] += v;
        __syncthreads();
    }
    if (tid < NB) blocksum[tid] = s[tid] - c;  // exclusive
}

__global__ void k_scanC(int* __restrict__ rowstart, int* __restrict__ cursor,
                        const int* __restrict__ blocksum, int N, int E) {
    int i = blockIdx.x * 256 + threadIdx.x;
    if (i < N) {
        int v = rowstart[i] + blocksum[blockIdx.x];
        rowstart[i] = v;
        cursor[i] = v;
    }
    if (i == 0) rowstart[N] = E;
}

// ---------------------------------------------------------------------------
// K3e: scatter edges into CSR order, packing (src, a_src[src]+a_edge[e]).
// ---------------------------------------------------------------------------
__global__ void k_scatter(const int* __restrict__ src, const int* __restrict__ dst,
                          const int* __restrict__ travel,
                          const float* __restrict__ dur,
                          const float* __restrict__ tst,
                          const float* __restrict__ tet,
                          const float* __restrict__ a_src,
                          const float* __restrict__ tbl,
                          int* __restrict__ cursor,
                          int2* __restrict__ epk, int E) {
    int i = blockIdx.x * blockDim.x + threadIdx.x;
    int stride = gridDim.x * blockDim.x;
    float c0 = tbl[136], c1 = tbl[137], c2 = tbl[138];
    for (int e = i; e < E; e += stride) {
        int s = src[e], d = dst[e];
        float ap = a_src[s] + tbl[128 + travel[e]]
                 + c0 * dur[e] + c1 * tst[e] + c2 * tet[e];
        int pos = atomicAdd(&cursor[d], 1);
        int2 p;
        p.x = s;
        p.y = __float_as_int(ap);
        epk[pos] = p;
    }
}

// ---------------------------------------------------------------------------
// K3f: atomic-free aggregation. One wave per dst node, 4 edges in flight
// (16 lanes x float4 each = 256B per edge). Fuses /denom + b_gat + relu.
// ---------------------------------------------------------------------------
__global__ void k_gather(const int2* __restrict__ epk,
                         const int* __restrict__ rowstart,
                         const float* __restrict__ a_dst,
                         const float4* __restrict__ h4,
                         const float4* __restrict__ bg4,
                         float4* __restrict__ x2_4, int N) {
    int lane = threadIdx.x & 63;
    int wid = (blockIdx.x * blockDim.x + threadIdx.x) >> 6;
    int nw = (gridDim.x * blockDim.x) >> 6;
    int grp = lane >> 4;   // which of 4 edges
    int sub = lane & 15;   // which float4 of the hidden dim
    float4 bb = bg4[sub];
    for (int n = wid; n < N; n += nw) {
        int r0 = rowstart[n], r1 = rowstart[n + 1];
        float adst = a_dst[n];
        float ax = 0.f, ay = 0.f, az = 0.f, aw = 0.f, den = 0.f;
        for (int base = r0; base < r1; base += 4) {
            int e = base + grp;
            float ev = 0.f;
            float4 hv = make_float4(0.f, 0.f, 0.f, 0.f);
            if (e < r1) {
                int2 p = epk[e];
                float al = __int_as_float(p.y) + adst;
                al = al > 0.f ? al : 0.2f * al;
                ev = __expf(al);
                hv = h4[(size_t)p.x * 16 + sub];
            }
            ax += ev * hv.x; ay += ev * hv.y; az += ev * hv.z; aw += ev * hv.w;
            den += ev;
        }
#pragma unroll
        for (int off = 16; off < 64; off <<= 1) {
            ax += __shfl_xor(ax, off, 64);
            ay += __shfl_xor(ay, off, 64);
            az += __shfl_xor(az, off, 64);
            aw += __shfl_xor(aw, off, 64);
            den += __shfl_xor(den, off, 64);
        }
        if (lane < 16) {
            float dn = den > 1e-16f ? den : 1e-16f;
            float inv = 1.f / dn;
            float4 v;
            v.x = ax * inv + bb.x; v.y = ay * inv + bb.y;
            v.z = az * inv + bb.z; v.w = aw * inv + bb.w;
            v.x = v.x > 0.f ? v.x : 0.f;
            v.y = v.y > 0.f ? v.y : 0.f;
            v.z = v.z > 0.f ? v.z : 0.f;
            v.w = v.w > 0.f ? v.w : 0.f;
            x2_4[(size_t)n * 16 + lane] = v;
        }
    }
}

// ---------------------------------------------------------------------------
// K4: per-graph mean pool over x2. batch is sorted -> binary search range.
// ---------------------------------------------------------------------------
__global__ void k_pool(const float* __restrict__ x2,
                       const int* __restrict__ batch, int N,
                       float* __restrict__ pooled) {
    int g = blockIdx.x;
    int lane = threadIdx.x;
    int lo = 0, hi = N;
    while (lo < hi) { int mid = (lo + hi) >> 1; if (batch[mid] < g) lo = mid + 1; else hi = mid; }
    int start = lo;
    hi = N;
    while (lo < hi) { int mid = (lo + hi) >> 1; if (batch[mid] < g + 1) lo = mid + 1; else hi = mid; }
    int end = lo;
    float sum = 0.f;
    for (int n = start; n < end; n++) sum += x2[(size_t)n * 64 + lane];
    float cnt = (float)(end - start);
    pooled[g * 64 + lane] = sum / (cnt > 1.f ? cnt : 1.f);
}

// ---------------------------------------------------------------------------
// K5: logits = pooled @ W_fc + b_fc ; out = log_softmax(logits)
// ---------------------------------------------------------------------------
__global__ void k_fc(const float* __restrict__ pooled,
                     const float* __restrict__ W_fc,
                     const float* __restrict__ b_fc,
                     float* __restrict__ out, int G) {
    int lane = threadIdx.x & 63;
    int wid = (blockIdx.x * blockDim.x + threadIdx.x) >> 6;
    int nw = (gridDim.x * blockDim.x) >> 6;
    for (int g = wid; g < G; g += nw) {
        float p = pooled[g * 64 + lane];
        float logit[TARGET];
#pragma unroll
        for (int t = 0; t < TARGET; t++) {
            float v = p * W_fc[lane * TARGET + t];
#pragma unroll
            for (int o = 32; o > 0; o >>= 1) v += __shfl_xor(v, o, 64);
            logit[t] = v + b_fc[t];
        }
        float m = logit[0];
#pragma unroll
        for (int t = 1; t < TARGET; t++) m = fmaxf(m, logit[t]);
        float se = 0.f;
#pragma unroll
        for (int t = 0; t < TARGET; t++) se += expf(logit[t] - m);
        float lse = m + logf(se);
#pragma unroll
        for (int t = 0; t < TARGET; t++)
            if (lane == t) out[g * TARGET + t] = logit[t] - lse;
    }
}

extern "C" void kernel_launch(void* const* d_in, const int* in_sizes, int n_in,
                              void* d_out, int out_size, void* d_ws, size_t ws_size,
                              hipStream_t stream) {
    const int*   act        = (const int*)d_in[0];
    const int*   loc        = (const int*)d_in[1];
    const int*   travel     = (const int*)d_in[2];
    const float* dur        = (const float*)d_in[3];
    const float* tst        = (const float*)d_in[4];
    const float* tet        = (const float*)d_in[5];
    const int*   ei         = (const int*)d_in[6];
    const int*   batch      = (const int*)d_in[7];
    const float* emb_act    = (const float*)d_in[8];
    const float* emb_loc    = (const float*)d_in[9];
    const float* emb_travel = (const float*)d_in[10];
    const float* W_gat      = (const float*)d_in[11];
    const float* att_src    = (const float*)d_in[12];
    const float* att_dst    = (const float*)d_in[13];
    const float* W_edge     = (const float*)d_in[14];
    const float* att_edge   = (const float*)d_in[15];
    const float* b_gat      = (const float*)d_in[16];
    const float* W_fc       = (const float*)d_in[17];
    const float* b_fc       = (const float*)d_in[18];
    float* out = (float*)d_out;

    int N = in_sizes[0];
    int E = in_sizes[2];
    int G = out_size / TARGET;
    int NB = (N + 255) / 256;

    float* ws = (float*)d_ws;
    size_t off = 0;
    float* tbl      = ws + off; off += 256;
    float* h        = ws + off; off += (size_t)N * 64;   // 16B-aligned (off%4==0)
    float* x2       = ws + off; off += (size_t)N * 64;
    float* a_src    = ws + off; off += N;
    float* a_dst    = ws + off; off += N;
    int*   counts   = (int*)(ws + off); off += N;
    int*   rowstart = (int*)(ws + off); off += N + 2;
    int*   cursor   = (int*)(ws + off); off += N;
    int*   blocksum = (int*)(ws + off); off += 1024;
    int2*  epk      = (int2*)(ws + off); off += (size_t)E * 2;  // off even -> 8B aligned
    float* pooled   = ws + off; off += (size_t)G * 64;

    hipMemsetAsync(counts, 0, (size_t)N * sizeof(int), stream);

    k_tables<<<1, 128, 0, stream>>>(W_gat, att_src, att_dst, W_edge, att_edge,
                                    emb_travel, tbl);
    k_nodes<<<1024, 256, 0, stream>>>(act, loc, emb_act, emb_loc, W_gat, tbl,
                                      h, a_src, a_dst, N);
    k_hist<<<2048, 256, 0, stream>>>(ei + E, E, counts);
    k_scanA<<<NB, 256, 0, stream>>>(counts, N, rowstart, blocksum);
    k_scanB<<<1, 1024, 0, stream>>>(blocksum, NB);
    k_scanC<<<NB, 256, 0, stream>>>(rowstart, cursor, blocksum, N, E);
    k_scatter<<<2048, 256, 0, stream>>>(ei, ei + E, travel, dur, tst, tet,
                                        a_src, tbl, cursor, epk, E);
    k_gather<<<4096, 256, 0, stream>>>(epk, rowstart, a_dst,
                                       (const float4*)h, (const float4*)b_gat,
                                       (float4*)x2, N);
    k_pool<<<G, 64, 0, stream>>>(x2, batch, N, pooled);
    k_fc<<<256, 256, 0, stream>>>(pooled, W_fc, b_fc, out, G);
}

// Round 3
// 303.920 us; speedup vs baseline: 1.9121x; 1.2152x over previous
//
#include <hip/hip_runtime.h>
#include <math.h>

#define HIDDEN 64
#define TARGET 10

static __device__ __forceinline__ unsigned short f2bf(float f) {
    unsigned int u = __float_as_uint(f);
    u = (u + 0x7fffu + ((u >> 16) & 1u)) >> 16;   // RNE
    return (unsigned short)u;
}
static __device__ __forceinline__ float bf2f(unsigned short v) {
    return __uint_as_float((unsigned int)v << 16);
}

// ---------------------------------------------------------------------------
// K1: precompute small tables.
//  tbl[0..63]   = hw_src[k] = W_gat[k,:] . att_src   (a_src = x . hw_src)
//  tbl[64..127] = hw_dst[k] = W_gat[k,:] . att_dst
//  tbl[128..135]= tbl_travel[t] = emb_travel[t,:] . w_e[0:64]
//  tbl[136..138]= c0,c1,c2 = w_e[64..66]
// ---------------------------------------------------------------------------
__global__ void k_tables(const float* __restrict__ W_gat,
                         const float* __restrict__ att_src,
                         const float* __restrict__ att_dst,
                         const float* __restrict__ W_edge,
                         const float* __restrict__ att_edge,
                         const float* __restrict__ emb_travel,
                         float* __restrict__ tbl) {
    __shared__ float we_s[67];
    int t = threadIdx.x;
    if (t < 64) {
        float s1 = 0.f, s2 = 0.f;
        for (int j = 0; j < 64; j++) {
            float w = W_gat[t * 64 + j];
            s1 += w * att_src[j];
            s2 += w * att_dst[j];
        }
        tbl[t] = s1;
        tbl[64 + t] = s2;
    }
    if (t < 67) {
        float s = 0.f;
        for (int j = 0; j < 64; j++) s += W_edge[t * 64 + j] * att_edge[j];
        we_s[t] = s;
    }
    __syncthreads();
    if (t < 8) {
        float s = 0.f;
        for (int k = 0; k < 64; k++) s += emb_travel[t * 64 + k] * we_s[k];
        tbl[128 + t] = s;
    }
    if (t == 0) {
        tbl[136] = we_s[64];
        tbl[137] = we_s[65];
        tbl[138] = we_s[66];
    }
}

// ---------------------------------------------------------------------------
// K2: per-node, LDS-tiled register-blocked matmul.
// 64-node tile per block; 16x16 threads, each computes a 4x4 (node,col) tile.
//  x = relu(emb_act[act]+emb_loc[loc]); h = x @ W_gat (bf16 out)
//  a_src/a_dst folded in as reduction of the accumulator tile over cols.
// Pad 68 floats/row: float4-aligned, breaks stride-64 bank aliasing.
// ---------------------------------------------------------------------------
__global__ __launch_bounds__(256) void k_nodes(
        const int* __restrict__ act, const int* __restrict__ loc,
        const float* __restrict__ emb_act,
        const float* __restrict__ emb_loc,
        const float* __restrict__ W_gat,
        const float* __restrict__ att_src,
        const float* __restrict__ att_dst,
        unsigned short* __restrict__ hb,
        float* __restrict__ a_src, float* __restrict__ a_dst,
        int N) {
    __shared__ float xs[64][68];
    __shared__ float Wl[64][68];
    __shared__ int acts[64], locs[64];
    int tid = threadIdx.x;
    int base = blockIdx.x * 64;

    for (int i = tid; i < 4096; i += 256) Wl[i >> 6][i & 63] = W_gat[i];
    if (tid < 64) {
        int n = base + tid;
        acts[tid] = (n < N) ? act[n] : 0;
        locs[tid] = (n < N) ? loc[n] : 0;
    }
    __syncthreads();

    for (int i = tid; i < 1024; i += 256) {
        int r = i >> 4, k4 = i & 15;
        int n = base + r;
        float4 v = make_float4(0.f, 0.f, 0.f, 0.f);
        if (n < N) {
            float4 a = ((const float4*)emb_act)[acts[r] * 16 + k4];
            float4 b = ((const float4*)emb_loc)[locs[r] * 16 + k4];
            v.x = fmaxf(a.x + b.x, 0.f);
            v.y = fmaxf(a.y + b.y, 0.f);
            v.z = fmaxf(a.z + b.z, 0.f);
            v.w = fmaxf(a.w + b.w, 0.f);
        }
        *(float4*)&xs[r][k4 * 4] = v;
    }
    __syncthreads();

    int tx = tid & 15, ty = tid >> 4;
    float acc[4][4];
#pragma unroll
    for (int i = 0; i < 4; i++)
#pragma unroll
        for (int j = 0; j < 4; j++) acc[i][j] = 0.f;

#pragma unroll 4
    for (int k4 = 0; k4 < 16; k4++) {
        float4 xv[4], wv[4];
#pragma unroll
        for (int i = 0; i < 4; i++) xv[i] = *(const float4*)&xs[ty * 4 + i][k4 * 4];
#pragma unroll
        for (int kk = 0; kk < 4; kk++) wv[kk] = *(const float4*)&Wl[k4 * 4 + kk][tx * 4];
#pragma unroll
        for (int i = 0; i < 4; i++) {
            float xk0 = xv[i].x, xk1 = xv[i].y, xk2 = xv[i].z, xk3 = xv[i].w;
            acc[i][0] += xk0 * wv[0].x + xk1 * wv[1].x + xk2 * wv[2].x + xk3 * wv[3].x;
            acc[i][1] += xk0 * wv[0].y + xk1 * wv[1].y + xk2 * wv[2].y + xk3 * wv[3].y;
            acc[i][2] += xk0 * wv[0].z + xk1 * wv[1].z + xk2 * wv[2].z + xk3 * wv[3].z;
            acc[i][3] += xk0 * wv[0].w + xk1 * wv[1].w + xk2 * wv[2].w + xk3 * wv[3].w;
        }
    }

    // h (bf16) write: each thread covers rows ty*4..+3, cols tx*4..+3
#pragma unroll
    for (int i = 0; i < 4; i++) {
        int n = base + ty * 4 + i;
        if (n < N) {
            ushort4 hv;
            hv.x = f2bf(acc[i][0]); hv.y = f2bf(acc[i][1]);
            hv.z = f2bf(acc[i][2]); hv.w = f2bf(acc[i][3]);
            *(ushort4*)&hb[(size_t)n * 64 + tx * 4] = hv;
        }
    }

    // a_src/a_dst: reduce acc over cols. partial over this thread's 4 cols,
    // then xor-reduce across tx (tid bits 0..3).
    float4 as4 = ((const float4*)att_src)[tx];
    float4 ad4 = ((const float4*)att_dst)[tx];
    float ps[4], pd[4];
#pragma unroll
    for (int i = 0; i < 4; i++) {
        ps[i] = acc[i][0] * as4.x + acc[i][1] * as4.y + acc[i][2] * as4.z + acc[i][3] * as4.w;
        pd[i] = acc[i][0] * ad4.x + acc[i][1] * ad4.y + acc[i][2] * ad4.z + acc[i][3] * ad4.w;
    }
#pragma unroll
    for (int off = 1; off < 16; off <<= 1) {
#pragma unroll
        for (int i = 0; i < 4; i++) {
            ps[i] += __shfl_xor(ps[i], off, 64);
            pd[i] += __shfl_xor(pd[i], off, 64);
        }
    }
    if (tx == 0) {
#pragma unroll
        for (int i = 0; i < 4; i++) {
            int n = base + ty * 4 + i;
            if (n < N) { a_src[n] = ps[i]; a_dst[n] = pd[i]; }
        }
    }
}

// ---------------------------------------------------------------------------
// K3a: histogram of dst -> counts[N]
// ---------------------------------------------------------------------------
__global__ void k_hist(const int* __restrict__ dst, int E,
                       int* __restrict__ counts) {
    int i = blockIdx.x * blockDim.x + threadIdx.x;
    int stride = gridDim.x * blockDim.x;
    for (int e = i; e < E; e += stride) atomicAdd(&counts[dst[e]], 1);
}

// ---------------------------------------------------------------------------
// K3b/c/d: two-level exclusive scan of counts -> rowstart[N+1], cursor[N]
// ---------------------------------------------------------------------------
__global__ void k_scanA(const int* __restrict__ counts, int N,
                        int* __restrict__ rowstart, int* __restrict__ blocksum) {
    __shared__ int s[256];
    int tid = threadIdx.x;
    int i = blockIdx.x * 256 + tid;
    int c = (i < N) ? counts[i] : 0;
    s[tid] = c;
    __syncthreads();
    for (int off = 1; off < 256; off <<= 1) {
        int v = 0;
        if (tid >= off) v = s[tid - off];
        __syncthreads();
        if (tid >= off) s[tid] += v;
        __syncthreads();
    }
    if (i < N) rowstart[i] = s[tid] - c;
    if (tid == 255) blocksum[blockIdx.x] = s[255];
}

__global__ void k_scanB(int* __restrict__ blocksum, int NB) {
    __shared__ int s[1024];
    int tid = threadIdx.x;
    int c = (tid < NB) ? blocksum[tid] : 0;
    s[tid] = c;
    __syncthreads();
    for (int off = 1; off < 1024; off <<= 1) {
        int v = 0;
        if (tid >= off) v = s[tid - off];
        __syncthreads();
        if (tid >= off) s[tid] += v;
        __syncthreads();
    }
    if (tid < NB) blocksum[tid] = s[tid] - c;
}

__global__ void k_scanC(int* __restrict__ rowstart, int* __restrict__ cursor,
                        const int* __restrict__ blocksum, int N, int E) {
    int i = blockIdx.x * 256 + threadIdx.x;
    if (i < N) {
        int v = rowstart[i] + blocksum[blockIdx.x];
        rowstart[i] = v;
        cursor[i] = v;
    }
    if (i == 0) rowstart[N] = E;
}

// ---------------------------------------------------------------------------
// K3e: scatter edges into CSR order, packing (src, a_src[src]+a_edge[e]).
// ---------------------------------------------------------------------------
__global__ void k_scatter(const int* __restrict__ src, const int* __restrict__ dst,
                          const int* __restrict__ travel,
                          const float* __restrict__ dur,
                          const float* __restrict__ tst,
                          const float* __restrict__ tet,
                          const float* __restrict__ a_src,
                          const float* __restrict__ tbl,
                          int* __restrict__ cursor,
                          int2* __restrict__ epk, int E) {
    int i = blockIdx.x * blockDim.x + threadIdx.x;
    int stride = gridDim.x * blockDim.x;
    float c0 = tbl[136], c1 = tbl[137], c2 = tbl[138];
    for (int e = i; e < E; e += stride) {
        int s = src[e], d = dst[e];
        float ap = a_src[s] + tbl[128 + travel[e]]
                 + c0 * dur[e] + c1 * tst[e] + c2 * tet[e];
        int pos = atomicAdd(&cursor[d], 1);
        int2 p;
        p.x = s;
        p.y = __float_as_int(ap);
        epk[pos] = p;
    }
}

// ---------------------------------------------------------------------------
// K3f: atomic-free aggregation. One wave per dst node, 4 edges in flight
// (16 lanes x ushort4-bf16 each = 128B per edge). Fuses /denom + b_gat + relu.
// ---------------------------------------------------------------------------
__global__ void k_gather(const int2* __restrict__ epk,
                         const int* __restrict__ rowstart,
                         const float* __restrict__ a_dst,
                         const ushort4* __restrict__ hb4,
                         const float4* __restrict__ bg4,
                         float4* __restrict__ x2_4, int N) {
    int lane = threadIdx.x & 63;
    int wid = (blockIdx.x * blockDim.x + threadIdx.x) >> 6;
    int nw = (gridDim.x * blockDim.x) >> 6;
    int grp = lane >> 4;   // which of 4 edges
    int sub = lane & 15;   // which ushort4 of the hidden dim
    float4 bb = bg4[sub];
    for (int n = wid; n < N; n += nw) {
        int r0 = rowstart[n], r1 = rowstart[n + 1];
        float adst = a_dst[n];
        float ax = 0.f, ay = 0.f, az = 0.f, aw = 0.f, den = 0.f;
        for (int base = r0; base < r1; base += 4) {
            int e = base + grp;
            if (e < r1) {
                int2 p = epk[e];
                float al = __int_as_float(p.y) + adst;
                al = al > 0.f ? al : 0.2f * al;
                float ev = __expf(al);
                ushort4 hu = hb4[(size_t)p.x * 16 + sub];
                ax += ev * bf2f(hu.x); ay += ev * bf2f(hu.y);
                az += ev * bf2f(hu.z); aw += ev * bf2f(hu.w);
                den += ev;
            }
        }
#pragma unroll
        for (int off = 16; off < 64; off <<= 1) {
            ax += __shfl_xor(ax, off, 64);
            ay += __shfl_xor(ay, off, 64);
            az += __shfl_xor(az, off, 64);
            aw += __shfl_xor(aw, off, 64);
            den += __shfl_xor(den, off, 64);
        }
        if (lane < 16) {
            float dn = den > 1e-16f ? den : 1e-16f;
            float inv = 1.f / dn;
            float4 v;
            v.x = ax * inv + bb.x; v.y = ay * inv + bb.y;
            v.z = az * inv + bb.z; v.w = aw * inv + bb.w;
            v.x = v.x > 0.f ? v.x : 0.f;
            v.y = v.y > 0.f ? v.y : 0.f;
            v.z = v.z > 0.f ? v.z : 0.f;
            v.w = v.w > 0.f ? v.w : 0.f;
            x2_4[(size_t)n * 16 + lane] = v;
        }
    }
}

// ---------------------------------------------------------------------------
// K4: per-graph mean pool over x2. batch is sorted -> binary search range.
// ---------------------------------------------------------------------------
__global__ void k_pool(const float* __restrict__ x2,
                       const int* __restrict__ batch, int N,
                       float* __restrict__ pooled) {
    int g = blockIdx.x;
    int lane = threadIdx.x;
    int lo = 0, hi = N;
    while (lo < hi) { int mid = (lo + hi) >> 1; if (batch[mid] < g) lo = mid + 1; else hi = mid; }
    int start = lo;
    hi = N;
    while (lo < hi) { int mid = (lo + hi) >> 1; if (batch[mid] < g + 1) lo = mid + 1; else hi = mid; }
    int end = lo;
    float sum = 0.f;
    for (int n = start; n < end; n++) sum += x2[(size_t)n * 64 + lane];
    float cnt = (float)(end - start);
    pooled[g * 64 + lane] = sum / (cnt > 1.f ? cnt : 1.f);
}

// ---------------------------------------------------------------------------
// K5: logits = pooled @ W_fc + b_fc ; out = log_softmax(logits)
// ---------------------------------------------------------------------------
__global__ void k_fc(const float* __restrict__ pooled,
                     const float* __restrict__ W_fc,
                     const float* __restrict__ b_fc,
                     float* __restrict__ out, int G) {
    int lane = threadIdx.x & 63;
    int wid = (blockIdx.x * blockDim.x + threadIdx.x) >> 6;
    int nw = (gridDim.x * blockDim.x) >> 6;
    for (int g = wid; g < G; g += nw) {
        float p = pooled[g * 64 + lane];
        float logit[TARGET];
#pragma unroll
        for (int t = 0; t < TARGET; t++) {
            float v = p * W_fc[lane * TARGET + t];
#pragma unroll
            for (int o = 32; o > 0; o >>= 1) v += __shfl_xor(v, o, 64);
            logit[t] = v + b_fc[t];
        }
        float m = logit[0];
#pragma unroll
        for (int t = 1; t < TARGET; t++) m = fmaxf(m, logit[t]);
        float se = 0.f;
#pragma unroll
        for (int t = 0; t < TARGET; t++) se += expf(logit[t] - m);
        float lse = m + logf(se);
#pragma unroll
        for (int t = 0; t < TARGET; t++)
            if (lane == t) out[g * TARGET + t] = logit[t] - lse;
    }
}

extern "C" void kernel_launch(void* const* d_in, const int* in_sizes, int n_in,
                              void* d_out, int out_size, void* d_ws, size_t ws_size,
                              hipStream_t stream) {
    const int*   act        = (const int*)d_in[0];
    const int*   loc        = (const int*)d_in[1];
    const int*   travel     = (const int*)d_in[2];
    const float* dur        = (const float*)d_in[3];
    const float* tst        = (const float*)d_in[4];
    const float* tet        = (const float*)d_in[5];
    const int*   ei         = (const int*)d_in[6];
    const int*   batch      = (const int*)d_in[7];
    const float* emb_act    = (const float*)d_in[8];
    const float* emb_loc    = (const float*)d_in[9];
    const float* emb_travel = (const float*)d_in[10];
    const float* W_gat      = (const float*)d_in[11];
    const float* att_src    = (const float*)d_in[12];
    const float* att_dst    = (const float*)d_in[13];
    const float* W_edge     = (const float*)d_in[14];
    const float* att_edge   = (const float*)d_in[15];
    const float* b_gat      = (const float*)d_in[16];
    const float* W_fc       = (const float*)d_in[17];
    const float* b_fc       = (const float*)d_in[18];
    float* out = (float*)d_out;

    int N = in_sizes[0];
    int E = in_sizes[2];
    int G = out_size / TARGET;
    int NB = (N + 255) / 256;

    float* ws = (float*)d_ws;
    size_t off = 0;
    float* tbl      = ws + off; off += 256;
    unsigned short* hb = (unsigned short*)(ws + off); off += (size_t)N * 32; // bf16 h
    float* x2       = ws + off; off += (size_t)N * 64;
    float* a_src    = ws + off; off += N;
    float* a_dst    = ws + off; off += N;
    int*   counts   = (int*)(ws + off); off += N;
    int*   rowstart = (int*)(ws + off); off += N + 2;
    int*   cursor   = (int*)(ws + off); off += N;
    int*   blocksum = (int*)(ws + off); off += 1024;
    int2*  epk      = (int2*)(ws + off); off += (size_t)E * 2;
    float* pooled   = ws + off; off += (size_t)G * 64;

    hipMemsetAsync(counts, 0, (size_t)N * sizeof(int), stream);

    k_tables<<<1, 128, 0, stream>>>(W_gat, att_src, att_dst, W_edge, att_edge,
                                    emb_travel, tbl);
    k_nodes<<<(N + 63) / 64, 256, 0, stream>>>(act, loc, emb_act, emb_loc, W_gat,
                                               att_src, att_dst, hb, a_src, a_dst, N);
    k_hist<<<2048, 256, 0, stream>>>(ei + E, E, counts);
    k_scanA<<<NB, 256, 0, stream>>>(counts, N, rowstart, blocksum);
    k_scanB<<<1, 1024, 0, stream>>>(blocksum, NB);
    k_scanC<<<NB, 256, 0, stream>>>(rowstart, cursor, blocksum, N, E);
    k_scatter<<<2048, 256, 0, stream>>>(ei, ei + E, travel, dur, tst, tet,
                                        a_src, tbl, cursor, epk, E);
    k_gather<<<4096, 256, 0, stream>>>(epk, rowstart, a_dst,
                                       (const ushort4*)hb, (const float4*)b_gat,
                                       (float4*)x2, N);
    k_pool<<<G, 64, 0, stream>>>(x2, batch, N, pooled);
    k_fc<<<256, 256, 0, stream>>>(pooled, W_fc, b_fc, out, G);
}